// Round 9
// baseline (127.239 us; speedup 1.0000x reference)
//
#include <hip/hip_runtime.h>
#include <hip/hip_bf16.h>

#define BATCH 4096
#define IN_DIM 3072
#define HID 1024
#define NSTEP 8

typedef __attribute__((ext_vector_type(8))) short short8;
typedef __attribute__((ext_vector_type(4))) float f32x4;
typedef __attribute__((ext_vector_type(4))) unsigned short ushort4v;

__device__ __forceinline__ void gload_lds16(const void* g, void* lds) {
  __builtin_amdgcn_global_load_lds(
      (const __attribute__((address_space(1))) void*)g,
      (__attribute__((address_space(3))) void*)lds, 16, 0, 0);
}

__device__ __forceinline__ unsigned short f32_to_bf16(float f) {
  unsigned int u = __builtin_bit_cast(unsigned int, f);
  unsigned int r = u + 0x7fffu + ((u >> 16) & 1u);
  return (unsigned short)(r >> 16);
}

__device__ __forceinline__ float bf16_to_f32(unsigned short u) {
  return __builtin_bit_cast(float, (unsigned int)u << 16);
}

// compiler-motion fence + HW barrier + scheduler pin
#define BARX()                          \
  do {                                  \
    asm volatile("" ::: "memory");      \
    __builtin_amdgcn_s_barrier();       \
    __builtin_amdgcn_sched_barrier(0);  \
  } while (0)

#define LGKM0()                                        \
  do {                                                 \
    asm volatile("s_waitcnt lgkmcnt(0)" ::: "memory"); \
    __builtin_amdgcn_sched_barrier(0);                 \
  } while (0)

// fused f32 -> bf16 conversion of x, We, Wd (one launch)
__global__ void cvt3_kernel(const float* __restrict__ a,
                            const float* __restrict__ b,
                            const float* __restrict__ c,
                            unsigned short* __restrict__ da,
                            unsigned short* __restrict__ db,
                            unsigned short* __restrict__ dc, int na, int nb,
                            int nc) {
  const int total = na + nb + nc;
  const int stride = gridDim.x * blockDim.x;
  for (int i = blockIdx.x * blockDim.x + threadIdx.x; i < total; i += stride) {
    const float* s;
    unsigned short* d;
    int j = i;
    if (j < na) {
      s = a; d = da;
    } else if (j < na + nb) {
      s = b; d = db; j -= na;
    } else {
      s = c; d = dc; j -= na + nb;
    }
    const float4 v = reinterpret_cast<const float4*>(s)[j];
    ushort4v o;
    o.x = f32_to_bf16(v.x);
    o.y = f32_to_bf16(v.y);
    o.z = f32_to_bf16(v.z);
    o.w = f32_to_bf16(v.w);
    reinterpret_cast<ushort4v*>(d)[j] = o;
  }
}

// 4-way split-K reduce (bf16 partials) + bias + RK4 nmODE.
// part = 4 stacked [4096,1024] bf16 partials. Writes y f32 (NT) + bf16.
__global__ __launch_bounds__(256) void ode4h_kernel(
    const unsigned short* __restrict__ part, const float* __restrict__ be,
    float* __restrict__ hid, unsigned short* __restrict__ hb, int n4) {
  const float dt = 1.0f / (float)NSTEP;
  const float h2 = 0.5f * dt, hd = dt, h6 = dt / 6.0f;
  const size_t seg = (size_t)BATCH * HID / 4;  // ushort4 units per partial
  const ushort4v* p4 = reinterpret_cast<const ushort4v*>(part);
  int stride = gridDim.x * blockDim.x;
  for (int i = blockIdx.x * blockDim.x + threadIdx.x; i < n4; i += stride) {
    const ushort4v a4 = p4[i];
    const ushort4v b4 = p4[i + seg];
    const ushort4v c4 = p4[i + 2 * seg];
    const ushort4v d4 = p4[i + 3 * seg];
    const float4 e4 = reinterpret_cast<const float4*>(be)[i & (HID / 4 - 1)];
    float g[4];
#pragma unroll
    for (int e = 0; e < 4; ++e)
      g[e] = bf16_to_f32(a4[e]) + bf16_to_f32(b4[e]) + bf16_to_f32(c4[e]) +
             bf16_to_f32(d4[e]);
    g[0] += e4.x; g[1] += e4.y; g[2] += e4.z; g[3] += e4.w;
    float y[4] = {0.0f, 0.0f, 0.0f, 0.0f};
#pragma unroll 1
    for (int s = 0; s < NSTEP; ++s) {
      float k1[4], k2[4], k3[4], k4[4];
#pragma unroll
      for (int e = 0; e < 4; ++e) {
        float t = __sinf(y[e] + g[e]);
        k1[e] = t * t - y[e];
      }
#pragma unroll
      for (int e = 0; e < 4; ++e) {
        float yy = fmaf(h2, k1[e], y[e]);
        float t = __sinf(yy + g[e]);
        k2[e] = t * t - yy;
      }
#pragma unroll
      for (int e = 0; e < 4; ++e) {
        float yy = fmaf(h2, k2[e], y[e]);
        float t = __sinf(yy + g[e]);
        k3[e] = t * t - yy;
      }
#pragma unroll
      for (int e = 0; e < 4; ++e) {
        float yy = fmaf(hd, k3[e], y[e]);
        float t = __sinf(yy + g[e]);
        k4[e] = t * t - yy;
      }
#pragma unroll
      for (int e = 0; e < 4; ++e) {
        float ks = k1[e] + 2.0f * (k2[e] + k3[e]) + k4[e];
        y[e] = fmaf(h6, ks, y[e]);
      }
    }
    f32x4 o4;
    o4[0] = y[0]; o4[1] = y[1]; o4[2] = y[2]; o4[3] = y[3];
    __builtin_nontemporal_store(o4, &reinterpret_cast<f32x4*>(hid)[i]);
    ushort4v ob;
    ob.x = f32_to_bf16(y[0]);
    ob.y = f32_to_bf16(y[1]);
    ob.z = f32_to_bf16(y[2]);
    ob.w = f32_to_bf16(y[3]);
    reinterpret_cast<ushort4v*>(hb)[i] = ob;
  }
}

// 8-phase NT GEMM, single barrier per phase, death-ordered restage.
// BM=256 x BN, BK=64, 8 waves (2 row x 4 col), per-wave 128 x BN/4.
// Round lifetimes (per tile in buf b): A{0,2} read ph1, A{1,3} ph3, B ph1-2.
// Stage plan (>=2-phase gap after last read): ph1 -> t+1{1,3}; ph3 -> t+2{0,2};
// ph4 -> t+2{B rounds} then vmcnt(R-2) publishes t+1 (loads issued >=3 phases
// earlier stay in flight across barriers; never drained to 0).
// Row&7 granule XOR swizzle (rule #21). EPI=1: bias+sigmoid f32 NT store.
// EPI=2: raw bf16 partial store at (ushort*)Cout + sk*M*Nout.
template <int BN, int NSK, int EPI>
__global__ __launch_bounds__(512, 2) void gemm8p(
    const unsigned short* __restrict__ A, const unsigned short* __restrict__ B,
    const float* __restrict__ bias, void* __restrict__ Cout, int Kstride,
    int Nout, int nbm, int nbn, int M) {
  constexpr int BM = 256, BK = 64;
  constexpr int CN = BN / 4;            // per-wave col extent (64 or 48)
  constexpr int AN = CN / 16;           // 4 or 3 acc frags n
  constexpr int NB2 = AN - 2;           // frags in B group 2 (2 or 1)
  constexpr int RB = BN / 64;           // B stage rounds (4 or 3)
  constexpr int R = 4 + RB;             // stage rounds per K-tile (8 or 7)

  __shared__ unsigned short As[2][BM * BK];
  __shared__ unsigned short Bs[2][BN * BK];

  const int tid = threadIdx.x;
  const int wave = tid >> 6;
  const int lane = tid & 63;
  const int wrow = wave >> 2;  // 0..1
  const int wcol = wave & 3;   // 0..3

  // chunked XCD swizzle (grid divisible by 8), bn-fastest, sk-slowest
  const int nwg = gridDim.x;
  const int swz = (blockIdx.x & 7) * (nwg >> 3) + (blockIdx.x >> 3);
  const int tiles = nbm * nbn;
  const int sk = swz / tiles;
  const int rem = swz % tiles;
  const int bn = rem % nbn;
  const int bm = rem / nbn;

  const int Klen = Kstride / NSK;
  const int ntT = Klen / BK;  // even (12 or 16)
  const unsigned short* Ablk = A + (size_t)bm * BM * Kstride + sk * Klen;
  const unsigned short* Bblk = B + (size_t)bn * BN * Kstride + sk * Klen;

  const int srr = tid >> 3;  // row within a 64-row stage round
  const int sgl = tid & 7;   // linear 16B granule

  auto STAGE = [&](int buf, int k0, int r) {
    if (r < 4) {
      const int row = r * 64 + srr;
      const int g = sgl ^ (row & 7);  // inverse-swizzled global source
      gload_lds16(Ablk + (size_t)row * Kstride + k0 + g * 8,
                  (void*)&As[buf][r * 4096 + wave * 512]);
    } else {
      const int row = (r - 4) * 64 + srr;
      const int g = sgl ^ (row & 7);
      gload_lds16(Bblk + (size_t)row * Kstride + k0 + g * 8,
                  (void*)&Bs[buf][(r - 4) * 4096 + wave * 512]);
    }
  };

  auto VMW = [&]() {
    if constexpr (R == 8)
      asm volatile("s_waitcnt vmcnt(6)" ::: "memory");
    else
      asm volatile("s_waitcnt vmcnt(5)" ::: "memory");
    __builtin_amdgcn_sched_barrier(0);
  };

  const int fr = lane & 15;
  const int hi = lane >> 4;

  short8 a[4][2], b1[2][2], b2[NB2][2];
  f32x4 acc[8][AN] = {};

  auto READ_A = [&](int buf, int mh) {
#pragma unroll
    for (int m = 0; m < 4; ++m) {
      const int row = wrow * 128 + (mh * 4 + m) * 16 + fr;
#pragma unroll
      for (int kk = 0; kk < 2; ++kk) {
        const int g = (kk * 4 + hi) ^ (row & 7);
        a[m][kk] =
            *reinterpret_cast<const short8*>(&As[buf][row * BK + g * 8]);
      }
    }
  };
  auto READ_B1 = [&](int buf) {
#pragma unroll
    for (int n = 0; n < 2; ++n) {
      const int row = wcol * CN + n * 16 + fr;
#pragma unroll
      for (int kk = 0; kk < 2; ++kk) {
        const int g = (kk * 4 + hi) ^ (row & 7);
        b1[n][kk] =
            *reinterpret_cast<const short8*>(&Bs[buf][row * BK + g * 8]);
      }
    }
  };
  auto READ_B2 = [&](int buf) {
#pragma unroll
    for (int j = 0; j < NB2; ++j) {
      const int row = wcol * CN + (2 + j) * 16 + fr;
#pragma unroll
      for (int kk = 0; kk < 2; ++kk) {
        const int g = (kk * 4 + hi) ^ (row & 7);
        b2[j][kk] =
            *reinterpret_cast<const short8*>(&Bs[buf][row * BK + g * 8]);
      }
    }
  };
  auto MM_B1 = [&](int mh) {
#pragma unroll
    for (int kk = 0; kk < 2; ++kk)
#pragma unroll
      for (int m = 0; m < 4; ++m)
#pragma unroll
        for (int n = 0; n < 2; ++n)
          acc[mh * 4 + m][n] = __builtin_amdgcn_mfma_f32_16x16x32_bf16(
              a[m][kk], b1[n][kk], acc[mh * 4 + m][n], 0, 0, 0);
  };
  auto MM_B2 = [&](int mh) {
#pragma unroll
    for (int kk = 0; kk < 2; ++kk)
#pragma unroll
      for (int m = 0; m < 4; ++m)
#pragma unroll
        for (int j = 0; j < NB2; ++j)
          acc[mh * 4 + m][2 + j] = __builtin_amdgcn_mfma_f32_16x16x32_bf16(
              a[m][kk], b2[j][kk], acc[mh * 4 + m][2 + j], 0, 0, 0);
  };

  // One K-tile t from buf b. kn = next tile's k-offset (-> buf b^1),
  // kn2 = tile t+2's k-offset (-> buf b). Single barrier per phase.
  auto HALF = [&](int b, int kn, int kn2) {
    // ph1: reads A0+B1 of t; stage t+1 rounds {1,3} (dead since prev ph3)
    READ_A(b, 0);
    READ_B1(b);
    STAGE(b ^ 1, kn, 1);
    STAGE(b ^ 1, kn, 3);
    BARX(); LGKM0();
    __builtin_amdgcn_s_setprio(1); MM_B1(0);
    __builtin_amdgcn_s_setprio(0);
    // ph2: reads B2
    READ_B2(b);
    BARX(); LGKM0();
    __builtin_amdgcn_s_setprio(1); MM_B2(0);
    __builtin_amdgcn_s_setprio(0);
    // ph3: reads A1; stage t+2 rounds {0,2} (A{0,2} dead since ph1)
    READ_A(b, 1);
    STAGE(b, kn2, 0);
    STAGE(b, kn2, 2);
    BARX(); LGKM0();
    __builtin_amdgcn_s_setprio(1); MM_B2(1);
    __builtin_amdgcn_s_setprio(0);
    // ph4: stage t+2 B rounds (dead since ph2); counted vmcnt publishes t+1
#pragma unroll
    for (int r = 4; r < R; ++r) STAGE(b, kn2, r);
    VMW();
    BARX();
    __builtin_amdgcn_s_setprio(1); MM_B1(1);
    __builtin_amdgcn_s_setprio(0);
  };

  // prologue: tile 0 fully; tile 1 except rounds {1,3}; publish tile 0
#pragma unroll
  for (int r = 0; r < R; ++r) STAGE(0, 0, r);
  STAGE(1, BK, 0);
  STAGE(1, BK, 2);
#pragma unroll
  for (int r = 4; r < R; ++r) STAGE(1, BK, r);
  VMW();
  BARX();

#pragma unroll 1
  for (int t = 0; t < ntT; ++t) {
    const int b = t & 1;
    const int kn = ((t + 1 == ntT) ? 0 : t + 1) * BK;
    const int kn2 = ((t + 2 >= ntT) ? t + 2 - ntT : t + 2) * BK;
    HALF(b, kn, kn2);
  }

  // epilogue: C/D layout col=lane&15, row=(lane>>4)*4+reg (m89-verified)
  const int rowbase = bm * BM + wrow * 128 + hi * 4;
  const int colbase = bn * BN + wcol * CN + fr;

#pragma unroll
  for (int m = 0; m < 8; ++m)
#pragma unroll
    for (int n = 0; n < AN; ++n) {
      float bv = 0.0f;
      if constexpr (EPI == 1) bv = bias[colbase + n * 16];
#pragma unroll
      for (int r = 0; r < 4; ++r) {
        float v = acc[m][n][r] + bv;
        size_t idx = (size_t)(rowbase + m * 16 + r) * Nout + (colbase + n * 16);
        if constexpr (EPI == 1) {
          v = 1.0f / (1.0f + __expf(-v));
          __builtin_nontemporal_store(v, &((float*)Cout)[idx]);
        } else {
          unsigned short* Hp =
              (unsigned short*)Cout + (size_t)sk * M * Nout;
          __builtin_nontemporal_store(f32_to_bf16(v), &Hp[idx]);
        }
      }
    }
}

extern "C" void kernel_launch(void* const* d_in, const int* in_sizes, int n_in,
                              void* d_out, int out_size, void* d_ws,
                              size_t ws_size, hipStream_t stream) {
  const float* x = (const float*)d_in[0];
  const float* We = (const float*)d_in[1];
  const float* be = (const float*)d_in[2];
  const float* Wd = (const float*)d_in[3];
  const float* bd = (const float*)d_in[4];

  float* out = (float*)d_out;                 // [4096,3072]
  float* hid = out + (size_t)BATCH * IN_DIM;  // [4096,1024]
  // bf16 split-K partials (4 x 8.4MB = 33.6MB) live at the front of d_out
  // (out region is 50MB; hid region untouched). GEMM2 overwrites them last.
  unsigned short* part = (unsigned short*)out;

  unsigned short* xb = (unsigned short*)d_ws;          // bf16 x   [4096,3072]
  unsigned short* Web = xb + (size_t)BATCH * IN_DIM;   // bf16 We  [1024,3072]
  unsigned short* Wdb = Web + (size_t)HID * IN_DIM;    // bf16 Wd  [3072,1024]
  unsigned short* hb = Wdb + (size_t)IN_DIM * HID;     // bf16 hid [4096,1024]

  cvt3_kernel<<<2048, 256, 0, stream>>>(
      x, We, Wd, xb, Web, Wdb, BATCH * IN_DIM / 4, HID * IN_DIM / 4,
      IN_DIM * HID / 4);

  // GEMM1: bf16 partials of x @ We^T. 256x256, BK=64, split-K=4 -> 256 blocks
  gemm8p<256, 4, 2><<<256, 512, 0, stream>>>(xb, Web, nullptr, part, IN_DIM,
                                             HID, BATCH / 256, HID / 256,
                                             BATCH);

  // ODE: gamma = p0+p1+p2+p3+be, RK4 -> hid f32 (NT) + hb bf16
  ode4h_kernel<<<2048, 256, 0, stream>>>(part, be, hid, hb, BATCH * HID / 4);

  // GEMM2: out = sigmoid(y @ Wd^T + bd). 256x192 -> 16x16 = 256 blocks
  gemm8p<192, 1, 1><<<256, 512, 0, stream>>>(hb, Wdb, bd, out, HID, IN_DIM,
                                             BATCH / 256, IN_DIM / 192, BATCH);
}

// Round 10
// 116.624 us; speedup vs baseline: 1.0910x; 1.0910x over previous
//
#include <hip/hip_runtime.h>
#include <hip/hip_bf16.h>

#define BATCH 4096
#define IN_DIM 3072
#define HID 1024
#define NSTEP 8

typedef __attribute__((ext_vector_type(8))) short short8;
typedef __attribute__((ext_vector_type(4))) float f32x4;
typedef __attribute__((ext_vector_type(4))) unsigned short ushort4v;

__device__ __forceinline__ void gload_lds16(const void* g, void* lds) {
  __builtin_amdgcn_global_load_lds(
      (const __attribute__((address_space(1))) void*)g,
      (__attribute__((address_space(3))) void*)lds, 16, 0, 0);
}

__device__ __forceinline__ unsigned short f32_to_bf16(float f) {
  unsigned int u = __builtin_bit_cast(unsigned int, f);
  unsigned int r = u + 0x7fffu + ((u >> 16) & 1u);
  return (unsigned short)(r >> 16);
}

// compiler-motion fence + HW barrier + scheduler pin
#define BARX()                          \
  do {                                  \
    asm volatile("" ::: "memory");      \
    __builtin_amdgcn_s_barrier();       \
    __builtin_amdgcn_sched_barrier(0);  \
  } while (0)

#define LGKM0()                                        \
  do {                                                 \
    asm volatile("s_waitcnt lgkmcnt(0)" ::: "memory"); \
    __builtin_amdgcn_sched_barrier(0);                 \
  } while (0)

#define VMCNT(N)                                            \
  do {                                                      \
    asm volatile("s_waitcnt vmcnt(" #N ")" ::: "memory");   \
    __builtin_amdgcn_sched_barrier(0);                      \
  } while (0)

// fused f32 -> bf16 conversion of x, We, Wd (one launch)
__global__ void cvt3_kernel(const float* __restrict__ a,
                            const float* __restrict__ b,
                            const float* __restrict__ c,
                            unsigned short* __restrict__ da,
                            unsigned short* __restrict__ db,
                            unsigned short* __restrict__ dc, int na, int nb,
                            int nc) {
  const int total = na + nb + nc;
  const int stride = gridDim.x * blockDim.x;
  for (int i = blockIdx.x * blockDim.x + threadIdx.x; i < total; i += stride) {
    const float* s;
    unsigned short* d;
    int j = i;
    if (j < na) {
      s = a; d = da;
    } else if (j < na + nb) {
      s = b; d = db; j -= na;
    } else {
      s = c; d = dc; j -= na + nb;
    }
    const float4 v = reinterpret_cast<const float4*>(s)[j];
    ushort4v o;
    o.x = f32_to_bf16(v.x);
    o.y = f32_to_bf16(v.y);
    o.z = f32_to_bf16(v.z);
    o.w = f32_to_bf16(v.w);
    reinterpret_cast<ushort4v*>(d)[j] = o;
  }
}

// Split-K2 reduce (p0+p1+bias) + RK4 nmODE. Writes y f32 (NT) + bf16.
__global__ __launch_bounds__(256) void ode_kernel(
    const float* __restrict__ p0, const float* __restrict__ p1,
    const float* __restrict__ be, float* __restrict__ hid,
    unsigned short* __restrict__ hb, int n4) {
  const float dt = 1.0f / (float)NSTEP;
  const float h2 = 0.5f * dt, hd = dt, h6 = dt / 6.0f;
  int stride = gridDim.x * blockDim.x;
  for (int i = blockIdx.x * blockDim.x + threadIdx.x; i < n4; i += stride) {
    const float4 a4 = reinterpret_cast<const float4*>(p0)[i];
    const float4 b4 = reinterpret_cast<const float4*>(p1)[i];
    const float4 e4 = reinterpret_cast<const float4*>(be)[i & (HID / 4 - 1)];
    float g[4] = {a4.x + b4.x + e4.x, a4.y + b4.y + e4.y,
                  a4.z + b4.z + e4.z, a4.w + b4.w + e4.w};
    float y[4] = {0.0f, 0.0f, 0.0f, 0.0f};
#pragma unroll 1
    for (int s = 0; s < NSTEP; ++s) {
      float k1[4], k2[4], k3[4], k4[4];
#pragma unroll
      for (int e = 0; e < 4; ++e) {
        float t = __sinf(y[e] + g[e]);
        k1[e] = t * t - y[e];
      }
#pragma unroll
      for (int e = 0; e < 4; ++e) {
        float yy = fmaf(h2, k1[e], y[e]);
        float t = __sinf(yy + g[e]);
        k2[e] = t * t - yy;
      }
#pragma unroll
      for (int e = 0; e < 4; ++e) {
        float yy = fmaf(h2, k2[e], y[e]);
        float t = __sinf(yy + g[e]);
        k3[e] = t * t - yy;
      }
#pragma unroll
      for (int e = 0; e < 4; ++e) {
        float yy = fmaf(hd, k3[e], y[e]);
        float t = __sinf(yy + g[e]);
        k4[e] = t * t - yy;
      }
#pragma unroll
      for (int e = 0; e < 4; ++e) {
        float ks = k1[e] + 2.0f * (k2[e] + k3[e]) + k4[e];
        y[e] = fmaf(h6, ks, y[e]);
      }
    }
    f32x4 o4;
    o4[0] = y[0]; o4[1] = y[1]; o4[2] = y[2]; o4[3] = y[3];
    __builtin_nontemporal_store(o4, &reinterpret_cast<f32x4*>(hid)[i]);
    ushort4v ob;
    ob.x = f32_to_bf16(y[0]);
    ob.y = f32_to_bf16(y[1]);
    ob.z = f32_to_bf16(y[2]);
    ob.w = f32_to_bf16(y[3]);
    reinterpret_cast<ushort4v*>(hb)[i] = ob;
  }
}

// GEMM1: partials of x @ We^T. BM=256, BN=128, BK=64, split-K=2, 8 waves
// (2x4), per-wave 128x32. Two double-barrier phases per K-tile:
//   ph1: read A0+B of t; stage t+1{0,2,4,5}; vmcnt(4) [publish t{1,3}];
//        BARX; lgkm0; MFMA A0xB; BARX.
//   ph2: read A1 of t;   stage t+1{1,3};     vmcnt(2) [publish t+1{0,2,4,5}];
//        BARX; lgkm0; MFMA A1xB; BARX.
// All stages obey the 2-barrier rule (region staged >=2 barriers after its
// last ds_read). Counted vmcnt throughout (never 0 in loop). Row&7 granule
// XOR swizzle (rule #21). f32 partial at Cout + sk*BATCH*HID (coalesced).
__global__ __launch_bounds__(512, 2) void gemm1k(
    const unsigned short* __restrict__ A, const unsigned short* __restrict__ B,
    float* __restrict__ Cout) {
  constexpr int BM = 256, BN = 128, BK = 64;
  constexpr int Kstride = IN_DIM;       // 3072
  constexpr int Klen = Kstride / 2;     // 1536
  constexpr int ntT = Klen / BK;        // 24
  constexpr int nbm = BATCH / BM;       // 16
  constexpr int nbn = HID / BN;         // 8

  __shared__ unsigned short As[2][BM * BK];
  __shared__ unsigned short Bs[2][BN * BK];

  const int tid = threadIdx.x;
  const int wave = tid >> 6;
  const int lane = tid & 63;
  const int wrow = wave >> 2;  // 0..1 -> 128 rows
  const int wcol = wave & 3;   // 0..3 -> 32 cols

  const int nwg = gridDim.x;  // 256
  const int swz = (blockIdx.x & 7) * (nwg >> 3) + (blockIdx.x >> 3);
  const int tiles = nbm * nbn;  // 128
  const int sk = swz / tiles;
  const int rem = swz % tiles;
  const int bn = rem % nbn;
  const int bm = rem / nbn;

  const unsigned short* Ablk = A + (size_t)bm * BM * Kstride + sk * Klen;
  const unsigned short* Bblk = B + (size_t)bn * BN * Kstride + sk * Klen;

  const int srr = tid >> 3;  // 64 rows per stage round
  const int sgl = tid & 7;

  // rounds: 0..3 = A (64 rows each), 4..5 = B (64 rows each)
  auto STAGE = [&](int buf, int k0, int r) {
    if (r < 4) {
      const int row = r * 64 + srr;
      const int g = sgl ^ (row & 7);
      gload_lds16(Ablk + (size_t)row * Kstride + k0 + g * 8,
                  (void*)&As[buf][r * 4096 + wave * 512]);
    } else {
      const int row = (r - 4) * 64 + srr;
      const int g = sgl ^ (row & 7);
      gload_lds16(Bblk + (size_t)row * Kstride + k0 + g * 8,
                  (void*)&Bs[buf][(r - 4) * 4096 + wave * 512]);
    }
  };

  const int fr = lane & 15;
  const int hi = lane >> 4;

  short8 a[4][2], b1[2][2];
  f32x4 acc[8][2] = {};

  auto READ_A = [&](int buf, int mh) {
#pragma unroll
    for (int m = 0; m < 4; ++m) {
      const int row = wrow * 128 + (mh * 4 + m) * 16 + fr;
#pragma unroll
      for (int kk = 0; kk < 2; ++kk) {
        const int g = (kk * 4 + hi) ^ (row & 7);
        a[m][kk] =
            *reinterpret_cast<const short8*>(&As[buf][row * BK + g * 8]);
      }
    }
  };
  auto READ_B = [&](int buf) {
#pragma unroll
    for (int n = 0; n < 2; ++n) {
      const int row = wcol * 32 + n * 16 + fr;
#pragma unroll
      for (int kk = 0; kk < 2; ++kk) {
        const int g = (kk * 4 + hi) ^ (row & 7);
        b1[n][kk] =
            *reinterpret_cast<const short8*>(&Bs[buf][row * BK + g * 8]);
      }
    }
  };
  auto MM = [&](int mh) {
#pragma unroll
    for (int kk = 0; kk < 2; ++kk)
#pragma unroll
      for (int m = 0; m < 4; ++m)
#pragma unroll
        for (int n = 0; n < 2; ++n)
          acc[mh * 4 + m][n] = __builtin_amdgcn_mfma_f32_16x16x32_bf16(
              a[m][kk], b1[n][kk], acc[mh * 4 + m][n], 0, 0, 0);
  };

  // prologue: issue t0 in order {0,2,4,5} then {1,3}; publish first four
  STAGE(0, 0, 0); STAGE(0, 0, 2); STAGE(0, 0, 4); STAGE(0, 0, 5);
  STAGE(0, 0, 1); STAGE(0, 0, 3);
  VMCNT(2);
  BARX();

#pragma unroll 1
  for (int t = 0; t < ntT; ++t) {
    const int b = t & 1;
    const int kn = ((t + 1 == ntT) ? 0 : t + 1) * BK;  // dummy wrap on tail
    // ph1
    READ_A(b, 0);
    READ_B(b);
    STAGE(b ^ 1, kn, 0); STAGE(b ^ 1, kn, 2);
    STAGE(b ^ 1, kn, 4); STAGE(b ^ 1, kn, 5);
    VMCNT(4);  // publishes t{1,3}
    BARX(); LGKM0();
    __builtin_amdgcn_s_setprio(1); MM(0);
    __builtin_amdgcn_s_setprio(0); BARX();
    // ph2
    READ_A(b, 1);
    STAGE(b ^ 1, kn, 1); STAGE(b ^ 1, kn, 3);
    VMCNT(2);  // publishes t+1{0,2,4,5}
    BARX(); LGKM0();
    __builtin_amdgcn_s_setprio(1); MM(1);
    __builtin_amdgcn_s_setprio(0); BARX();
  }

  // epilogue: f32 partial, coalesced (16 lanes x 4B = 64B lines), cached
  const int rowbase = bm * BM + wrow * 128 + hi * 4;
  const int colbase = bn * BN + wcol * 32 + fr;
  float* Cblk = Cout + (size_t)sk * BATCH * HID;
#pragma unroll
  for (int m = 0; m < 8; ++m)
#pragma unroll
    for (int n = 0; n < 2; ++n)
#pragma unroll
      for (int r = 0; r < 4; ++r) {
        size_t idx =
            (size_t)(rowbase + m * 16 + r) * HID + (colbase + n * 16);
        Cblk[idx] = acc[m][n][r];
      }
}

// GEMM2: round-8 double-barrier 8-phase (verified 43us). BM=256 x BN=192,
// BK=64, 8 waves, per-wave 128x48 (AN=3). bias+sigmoid f32 NT epilogue.
template <int BN>
__global__ __launch_bounds__(512, 2) void gemm8p(
    const unsigned short* __restrict__ A, const unsigned short* __restrict__ B,
    const float* __restrict__ bias, float* __restrict__ Cout, int Kstride,
    int Nout, int nbm, int nbn) {
  constexpr int BM = 256, BK = 64;
  constexpr int CN = BN / 4;            // 48
  constexpr int AN = CN / 16;           // 3
  constexpr int NB2 = AN - 2;           // 1
  constexpr int RB = BN / 64;           // 3
  constexpr int R = 4 + RB;             // 7
  constexpr int VM = (R == 8) ? 2 : 1;  // 1

  __shared__ unsigned short As[2][BM * BK];
  __shared__ unsigned short Bs[2][BN * BK];

  const int tid = threadIdx.x;
  const int wave = tid >> 6;
  const int lane = tid & 63;
  const int wrow = wave >> 2;
  const int wcol = wave & 3;

  const int nwg = gridDim.x;
  const int swz = (blockIdx.x & 7) * (nwg >> 3) + (blockIdx.x >> 3);
  const int bn = swz % nbn;
  const int bm = swz / nbn;

  const int ntT = Kstride / BK;  // 16
  const unsigned short* Ablk = A + (size_t)bm * BM * Kstride;
  const unsigned short* Bblk = B + (size_t)bn * BN * Kstride;

  const int srr = tid >> 3;
  const int sgl = tid & 7;

  auto STAGE = [&](int buf, int k0, int r) {
    if (r < 4) {
      const int row = r * 64 + srr;
      const int g = sgl ^ (row & 7);
      gload_lds16(Ablk + (size_t)row * Kstride + k0 + g * 8,
                  (void*)&As[buf][r * 4096 + wave * 512]);
    } else {
      const int row = (r - 4) * 64 + srr;
      const int g = sgl ^ (row & 7);
      gload_lds16(Bblk + (size_t)row * Kstride + k0 + g * 8,
                  (void*)&Bs[buf][(r - 4) * 4096 + wave * 512]);
    }
  };

  auto VMW = [&]() {
    if constexpr (VM == 2)
      asm volatile("s_waitcnt vmcnt(2)" ::: "memory");
    else
      asm volatile("s_waitcnt vmcnt(1)" ::: "memory");
    __builtin_amdgcn_sched_barrier(0);
  };

  const int fr = lane & 15;
  const int hi = lane >> 4;

  short8 a[4][2], b1[2][2], b2[NB2][2];
  f32x4 acc[8][AN] = {};

  auto READ_A = [&](int buf, int mh) {
#pragma unroll
    for (int m = 0; m < 4; ++m) {
      const int row = wrow * 128 + (mh * 4 + m) * 16 + fr;
#pragma unroll
      for (int kk = 0; kk < 2; ++kk) {
        const int g = (kk * 4 + hi) ^ (row & 7);
        a[m][kk] =
            *reinterpret_cast<const short8*>(&As[buf][row * BK + g * 8]);
      }
    }
  };
  auto READ_B1 = [&](int buf) {
#pragma unroll
    for (int n = 0; n < 2; ++n) {
      const int row = wcol * CN + n * 16 + fr;
#pragma unroll
      for (int kk = 0; kk < 2; ++kk) {
        const int g = (kk * 4 + hi) ^ (row & 7);
        b1[n][kk] =
            *reinterpret_cast<const short8*>(&Bs[buf][row * BK + g * 8]);
      }
    }
  };
  auto READ_B2 = [&](int buf) {
#pragma unroll
    for (int j = 0; j < NB2; ++j) {
      const int row = wcol * CN + (2 + j) * 16 + fr;
#pragma unroll
      for (int kk = 0; kk < 2; ++kk) {
        const int g = (kk * 4 + hi) ^ (row & 7);
        b2[j][kk] =
            *reinterpret_cast<const short8*>(&Bs[buf][row * BK + g * 8]);
      }
    }
  };
  auto MM_B1 = [&](int mh) {
#pragma unroll
    for (int kk = 0; kk < 2; ++kk)
#pragma unroll
      for (int m = 0; m < 4; ++m)
#pragma unroll
        for (int n = 0; n < 2; ++n)
          acc[mh * 4 + m][n] = __builtin_amdgcn_mfma_f32_16x16x32_bf16(
              a[m][kk], b1[n][kk], acc[mh * 4 + m][n], 0, 0, 0);
  };
  auto MM_B2 = [&](int mh) {
#pragma unroll
    for (int kk = 0; kk < 2; ++kk)
#pragma unroll
      for (int m = 0; m < 4; ++m)
#pragma unroll
        for (int j = 0; j < NB2; ++j)
          acc[mh * 4 + m][2 + j] = __builtin_amdgcn_mfma_f32_16x16x32_bf16(
              a[m][kk], b2[j][kk], acc[mh * 4 + m][2 + j], 0, 0, 0);
  };

  auto HALF = [&](int b, int kn, int kn2) {
    // ph1
    READ_A(b, 0);
    READ_B1(b);
    STAGE(b ^ 1, kn, VM + 0); STAGE(b ^ 1, kn, VM + 1);
    BARX(); LGKM0();
    __builtin_amdgcn_s_setprio(1); MM_B1(0);
    __builtin_amdgcn_s_setprio(0); BARX();
    // ph2
    READ_B2(b);
    STAGE(b ^ 1, kn, VM + 2); STAGE(b ^ 1, kn, VM + 3);
    BARX(); LGKM0();
    __builtin_amdgcn_s_setprio(1); MM_B2(0);
    __builtin_amdgcn_s_setprio(0); BARX();
    // ph3
    READ_A(b, 1);
    STAGE(b ^ 1, kn, VM + 4); STAGE(b ^ 1, kn, VM + 5);
    BARX(); LGKM0();
    __builtin_amdgcn_s_setprio(1); MM_B2(1);
    __builtin_amdgcn_s_setprio(0); BARX();
    // ph4: restage this buffer's successor head; counted vmcnt publishes t+1
    STAGE(b, kn2, 0);
    if constexpr (VM == 2) STAGE(b, kn2, 1);
    VMW();
    BARX();
    __builtin_amdgcn_s_setprio(1); MM_B1(1);
    __builtin_amdgcn_s_setprio(0); BARX();
  };

#pragma unroll
  for (int r = 0; r < R; ++r) STAGE(0, 0, r);
  STAGE(1, BK, 0);
  if constexpr (VM == 2) STAGE(1, BK, 1);
  VMW();
  BARX();

#pragma unroll 1
  for (int it = 0; it < ntT / 2; ++it) {
    const int t0 = 2 * it;
    const int k1 = (t0 + 1) * BK;
    const int k2 = ((t0 + 2 == ntT) ? 0 : t0 + 2) * BK;
    const int k3 = ((t0 + 3 >= ntT) ? t0 + 3 - ntT : t0 + 3) * BK;
    HALF(0, k1, k2);
    HALF(1, k2, k3);
  }

  const int rowbase = bm * BM + wrow * 128 + hi * 4;
  const int colbase = bn * BN + wcol * CN + fr;
#pragma unroll
  for (int m = 0; m < 8; ++m)
#pragma unroll
    for (int n = 0; n < AN; ++n) {
      const float bv = bias[colbase + n * 16];
#pragma unroll
      for (int r = 0; r < 4; ++r) {
        float v = acc[m][n][r] + bv;
        v = 1.0f / (1.0f + __expf(-v));
        size_t idx = (size_t)(rowbase + m * 16 + r) * Nout + (colbase + n * 16);
        __builtin_nontemporal_store(v, &Cout[idx]);
      }
    }
}

extern "C" void kernel_launch(void* const* d_in, const int* in_sizes, int n_in,
                              void* d_out, int out_size, void* d_ws,
                              size_t ws_size, hipStream_t stream) {
  const float* x = (const float*)d_in[0];
  const float* We = (const float*)d_in[1];
  const float* be = (const float*)d_in[2];
  const float* Wd = (const float*)d_in[3];
  const float* bd = (const float*)d_in[4];

  float* out = (float*)d_out;                 // [4096,3072]
  float* hid = out + (size_t)BATCH * IN_DIM;  // [4096,1024]
  // split-K=2 f32 partials (33.6MB) in the out region (50MB); GEMM2 last.
  float* part = out;

  unsigned short* xb = (unsigned short*)d_ws;          // bf16 x   [4096,3072]
  unsigned short* Web = xb + (size_t)BATCH * IN_DIM;   // bf16 We  [1024,3072]
  unsigned short* Wdb = Web + (size_t)HID * IN_DIM;    // bf16 Wd  [3072,1024]
  unsigned short* hb = Wdb + (size_t)IN_DIM * HID;     // bf16 hid [4096,1024]

  cvt3_kernel<<<2048, 256, 0, stream>>>(
      x, We, Wd, xb, Web, Wdb, BATCH * IN_DIM / 4, HID * IN_DIM / 4,
      IN_DIM * HID / 4);

  // GEMM1: f32 partials of x @ We^T. 256x128, BK=64, split-K=2 -> 256 blocks
  gemm1k<<<256, 512, 0, stream>>>(xb, Web, part);

  // ODE: gamma = p0+p1+be, RK4 -> hid f32 (NT) + hb bf16
  ode_kernel<<<2048, 256, 0, stream>>>(part, part + (size_t)BATCH * HID, be,
                                       hid, hb, BATCH * HID / 4);

  // GEMM2: out = sigmoid(y @ Wd^T + bd). 256x192 -> 16x16 = 256 blocks
  gemm8p<192><<<256, 512, 0, stream>>>(hb, Wdb, bd, out, HID, IN_DIM,
                                       BATCH / 256, IN_DIM / 192);
}